// Round 6
// baseline (738.516 us; speedup 1.0000x reference)
//
#include <hip/hip_runtime.h>
#include <hip/hip_fp16.h>
#include <math.h>

// Problem constants (from reference)
#define B_TRAJ 16384
#define T_STEPS 60
#define D_IN 36
#define L_DIM 10
#define C_NUM 20
#define S_STAT 9
#define OUT_DIM 8
#define CH 12                 // steps per xproj chunk
#define NCHUNK 5              // 60 / 12
#define NG 16                 // trajs (groups) per 256-thread block
#define SCS 72                // scratch stride in floats (72%32==8 -> 2-way max on scalar ops)

#define LOG2E 1.4426950408889634f

typedef float f32x2 __attribute__((ext_vector_type(2)));
__device__ __forceinline__ f32x2 pkfma(f32x2 a, f32x2 b, f32x2 c) {
    // llvm.fma.v2f32 -> v_pk_fma_f32 on gfx950 (full-rate packed f32)
    return __builtin_elementwise_fma(a, b, c);
}
__device__ __forceinline__ float rcp_fast(float x) { return __builtin_amdgcn_rcpf(x); }
__device__ __forceinline__ float exp2_fast(float x) { return __builtin_amdgcn_exp2f(x); }
__device__ __forceinline__ float sigm_fast(float x) {
    return rcp_fast(1.0f + exp2_fast(x * -LOG2E));
}
__device__ __forceinline__ float tanh_fast(float x) {
    const float t = fminf(fmaxf(x * (2.0f * LOG2E), -30.0f), 30.0f);
    return fmaf(-2.0f, rcp_fast(exp2_fast(t) + 1.0f), 1.0f);
}
#define WFENCE() __builtin_amdgcn_wave_barrier()

// v10: concurrency restructure. 16 trajs per 256-thread block (16 lanes/traj,
// v9 scan math unchanged). xproj computed in CH=12-step chunks into a small
// LDS buffer at block-wide boundaries (x direct from global, L1-broadcast);
// layout [tt][g][col16][gate4] f16 so the scan reads u/r/n pre-acts in ONE
// ds_read_b64. MLP head accumulated on the fly at boundaries from a CH-deep
// y stash -> no 60-row stash. LDS 33KB, launch_bounds(256,4) -> 16 waves/CU
// (2.5x v9). Scan sync stays wave-local (in-order DS + wave_barrier).
__global__ __launch_bounds__(256, 4)
void dgm2_v10(
    const float* __restrict__ data,        // [B, T, D]
    const float* __restrict__ time_steps,  // [T]
    const float* __restrict__ static_data, // [B, S]
    const float* __restrict__ W_update,    // [46, 10]
    const float* __restrict__ b_update,
    const float* __restrict__ W_reset,     // [46, 10]
    const float* __restrict__ b_reset,
    const float* __restrict__ W_new,       // [46, 10]
    const float* __restrict__ b_new,
    const float* __restrict__ W_emit,      // [30, 20]
    const float* __restrict__ b_emit,
    const float* __restrict__ W_ode,       // [10, 10]
    const float* __restrict__ b_ode,
    const float* __restrict__ W_mlp,       // [609, 8]
    const float* __restrict__ b_mlp,
    float* __restrict__ out)               // [B, 8]
{
    __shared__ __align__(16) __half xb[CH * NG * 16 * 4];  // 24576 B: [tt][g][col16][gate4]
    __shared__ __align__(16) __half yb[CH * NG * 10];      //  3840 B: [tt][g][col10] y stash
    __shared__ __align__(16) float  sc[NG * SCS];          //  4608 B: per-group scratch
                                                            //   YI@0(16) YR@16(16) Y@32(16) Z@48(20)

    const int tid  = threadIdx.x;
    const int g    = tid >> 4;      // group = local traj
    const int q    = tid & 15;      // lane within group
    const int traj = blockIdx.x * NG + g;

    const bool qg = (q < 10);
    const int  qc = qg ? q : 0;     // clamped gate-col (lanes 10-15 read col 0: garbage-safe)

    float* gYI = sc + g * SCS;
    float* gYR = gYI + 16;
    float* gY  = gYI + 32;
    float* gZ  = gYI + 48;

    // ---- persistent per-thread state ----
    f32x2 y2[5];
#pragma unroll
    for (int k = 0; k < 5; ++k) y2[k] = (f32x2){0.0f, 0.0f};
    float yown = 0.0f;
    f32x2 p2[4];                    // running MLP-head partials (cols 2j, 2j+1) for t-row q
#pragma unroll
    for (int j = 0; j < 4; ++j) p2[j] = (f32x2){0.0f, 0.0f};
    gZ[q] = 0.0f;                   // carried unnormalized z; 0 => p=0 at t=0
    if (q < 4) gZ[16 + q] = 0.0f;

    // ---- boundary: compute xproj chunk c into xb ----
    // lane q handles old-cols c0=q (0..15) and c1=16+q (q<14); col space: 0-9 u, 10-19 r, 20-29 n.
    auto do_xproj = [&](int c) {
        const int  c0   = q;
        const bool has1 = (q < 14);
        const int  c1   = has1 ? 16 + q : 29;
        const float* W0 = (c0 < 10) ? W_update : W_reset;
        const int   cc0 = (c0 < 10) ? c0 : c0 - 10;
        const int   gt0 = (c0 < 10) ? 0 : 1;
        const float* W1 = (c1 < 20) ? W_reset : W_new;
        const int   cc1 = (c1 < 20) ? c1 - 10 : c1 - 20;
        const int   gt1 = (c1 < 20) ? 1 : 2;
        f32x2 wxp0[18], wxp1[18];   // x-part rows 10..45
#pragma unroll
        for (int j = 0; j < 18; ++j) {
            wxp0[j] = (f32x2){W0[(L_DIM + 2 * j) * L_DIM + cc0],
                              W0[(L_DIM + 2 * j + 1) * L_DIM + cc0]};
            const f32x2 v1 = (f32x2){W1[(L_DIM + 2 * j) * L_DIM + cc1],
                                     W1[(L_DIM + 2 * j + 1) * L_DIM + cc1]};
            wxp1[j] = has1 ? v1 : (f32x2){0.0f, 0.0f};
        }
        const float b0 = (c0 < 10) ? b_update[c0] : b_reset[c0 - 10];
        const float b1 = has1 ? ((c1 < 20) ? b_reset[c1 - 10] : b_new[c1 - 20]) : 0.0f;
        const float* xbase = data + ((size_t)traj * T_STEPS + c * CH) * D_IN;
        for (int tt = 0; tt < CH; ++tt) {
            const float* xr = xbase + tt * D_IN;
            f32x2 a0 = (f32x2){b0, 0.0f}, a1 = (f32x2){b1, 0.0f};
#pragma unroll
            for (int cq = 0; cq < 9; ++cq) {
                const float4 x4 = *reinterpret_cast<const float4*>(xr + cq * 4);
                const f32x2 xlo = (f32x2){x4.x, x4.y};
                const f32x2 xhi = (f32x2){x4.z, x4.w};
                a0 = pkfma(xlo, wxp0[2 * cq], a0);
                a0 = pkfma(xhi, wxp0[2 * cq + 1], a0);
                a1 = pkfma(xlo, wxp1[2 * cq], a1);
                a1 = pkfma(xhi, wxp1[2 * cq + 1], a1);
            }
            __half* dst = xb + (size_t)((tt * NG + g) * 16) * 4;
            dst[cc0 * 4 + gt0] = __float2half(a0.x + a0.y);
            if (has1) dst[cc1 * 4 + gt1] = __float2half(a1.x + a1.y);
        }
    };

    // ---- boundary: accumulate MLP-head partials from the chunk's y stash ----
    // lane q (<CH) owns t-row c*CH+q: p2 += y_t[k] * W_mlp[t*10+k][:]
    auto do_head = [&](int c) {
        if (q < CH) {
            const int t = c * CH + q;
            const __half2* yrow = reinterpret_cast<const __half2*>(yb + (q * NG + g) * 10);
            const float* wr = W_mlp + (size_t)t * (L_DIM * OUT_DIM);
#pragma unroll
            for (int k2 = 0; k2 < 5; ++k2) {
                const float2 yv = __half22float2(yrow[k2]);
                const float* w0 = wr + (2 * k2) * OUT_DIM;
                const float* w1 = wr + (2 * k2 + 1) * OUT_DIM;
#pragma unroll
                for (int j = 0; j < 4; ++j) {
                    p2[j] = pkfma((f32x2){yv.x, yv.x}, (f32x2){w0[2 * j], w0[2 * j + 1]}, p2[j]);
                    p2[j] = pkfma((f32x2){yv.y, yv.y}, (f32x2){w1[2 * j], w1[2 * j + 1]}, p2[j]);
                }
            }
        }
    };

    auto ldvec = [&](const float* p, f32x2* d) {
        const float4 a = *reinterpret_cast<const float4*>(p);
        const float4 b = *reinterpret_cast<const float4*>(p + 4);
        const float2 c = *reinterpret_cast<const float2*>(p + 8);
        d[0] = (f32x2){a.x, a.y}; d[1] = (f32x2){a.z, a.w};
        d[2] = (f32x2){b.x, b.y}; d[3] = (f32x2){b.z, b.w};
        d[4] = (f32x2){c.x, c.y};
    };

    do_xproj(0);
    __syncthreads();

    for (int c = 0; c < NCHUNK; ++c) {
        // ---- scan weights, chunk-scoped (reloaded per chunk: relieves regalloc
        //      across the boundary phases; L1-hot) ----
        f32x2 wode2[5], wu2[5], wr2[5], wn2[5];
#pragma unroll
        for (int j = 0; j < 5; ++j) {
            if (qg) {
                wode2[j] = (f32x2){W_ode[(2 * j) * L_DIM + q], W_ode[(2 * j + 1) * L_DIM + q]};
                wu2[j]   = (f32x2){W_update[(2 * j) * L_DIM + q], W_update[(2 * j + 1) * L_DIM + q]};
                wr2[j]   = (f32x2){W_reset[(2 * j) * L_DIM + q], W_reset[(2 * j + 1) * L_DIM + q]};
                wn2[j]   = (f32x2){W_new[(2 * j) * L_DIM + q], W_new[(2 * j + 1) * L_DIM + q]};
            } else {
                wode2[j] = wu2[j] = wr2[j] = wn2[j] = (f32x2){0.0f, 0.0f};
            }
        }
        const float bode = qg ? b_ode[q] : 0.0f;
        const int  e0  = q;
        const bool he1 = (q < 4);
        const int  e1  = he1 ? 16 + q : 19;
        f32x2 wez0[10], wez1[10], wey0[5], wey1[5];
#pragma unroll
        for (int j = 0; j < 10; ++j) {
            wez0[j] = (f32x2){W_emit[(2 * j) * C_NUM + e0], W_emit[(2 * j + 1) * C_NUM + e0]};
            const f32x2 v1 = (f32x2){W_emit[(2 * j) * C_NUM + e1], W_emit[(2 * j + 1) * C_NUM + e1]};
            wez1[j] = he1 ? v1 : (f32x2){0.0f, 0.0f};
        }
#pragma unroll
        for (int j = 0; j < 5; ++j) {
            wey0[j] = (f32x2){W_emit[(C_NUM + 2 * j) * C_NUM + e0],
                              W_emit[(C_NUM + 2 * j + 1) * C_NUM + e0]};
            const f32x2 v1 = (f32x2){W_emit[(C_NUM + 2 * j) * C_NUM + e1],
                                     W_emit[(C_NUM + 2 * j + 1) * C_NUM + e1]};
            wey1[j] = he1 ? v1 : (f32x2){0.0f, 0.0f};
        }
        const float be0 = b_emit[e0];
        const float be1 = he1 ? b_emit[e1] : 0.0f;

        // ---- scan CH steps (wave-local sync only) ----
        for (int tt = 0; tt < CH; ++tt) {
            const int t = c * CH + tt;
            const float dt = (t == 0) ? 0.01f : time_steps[t] - time_steps[t - 1];  // uniform -> s_loads

            // ODE (lane-local col): yi_q = y_q + tanh(b + y.Wode[:,q])*dt
            f32x2 g2 = (f32x2){bode, 0.0f};
#pragma unroll
            for (int k = 0; k < 5; ++k) g2 = pkfma(y2[k], wode2[k], g2);
            const float yis = fmaf(tanh_fast(g2.x + g2.y), dt, yown);
            gYI[q] = yis;
            WFENCE();
            f32x2 yi2[5];
            ldvec(gYI, yi2);

            // xproj: one b64 -> (u,r,n,pad) pre-activations for col q (bias folded)
            union { float2 f2; __half2 h2[2]; } xu;
            xu.f2 = *reinterpret_cast<const float2*>(xb + (size_t)((tt * NG + g) * 16 + qc) * 4);
            const float2 xg0 = __half22float2(xu.h2[0]);
            const float2 xg1 = __half22float2(xu.h2[1]);
            const float xau = xg0.x, xar = xg0.y, xan = xg1.x;

            f32x2 au2 = (f32x2){xau, 0.0f};
            f32x2 ar2 = (f32x2){xar, 0.0f};
#pragma unroll
            for (int k = 0; k < 5; ++k) {
                au2 = pkfma(yi2[k], wu2[k], au2);
                ar2 = pkfma(yi2[k], wr2[k], ar2);
            }
            const float u = sigm_fast(au2.x + au2.y);
            const float r = sigm_fast(ar2.x + ar2.y);
            gYR[q] = r * yis;
            WFENCE();
            f32x2 yr2[5];
            ldvec(gYR, yr2);

            // candidate + blend (lane-local)
            f32x2 an2 = (f32x2){xan, 0.0f};
#pragma unroll
            for (int k = 0; k < 5; ++k) an2 = pkfma(yr2[k], wn2[k], an2);
            const float nv = an2.x + an2.y;
            const float yn = fmaf(u, yis - nv, nv);
            yown = yn;
            gY[q] = yn;
            if (qg) yb[(tt * NG + g) * 10 + q] = __float2half(yn);   // stash for head
            WFENCE();
            ldvec(gY, y2);

            // emitter: logit_c = b_c + (z_prev . We_p[:,c])/sum(z) + y . We_y[:,c]
            f32x2 zz[10];
            {
                const float4 z0 = *reinterpret_cast<const float4*>(gZ);
                const float4 z1 = *reinterpret_cast<const float4*>(gZ + 4);
                const float4 z2 = *reinterpret_cast<const float4*>(gZ + 8);
                const float4 z3 = *reinterpret_cast<const float4*>(gZ + 12);
                const float4 z4 = *reinterpret_cast<const float4*>(gZ + 16);
                zz[0] = (f32x2){z0.x, z0.y}; zz[1] = (f32x2){z0.z, z0.w};
                zz[2] = (f32x2){z1.x, z1.y}; zz[3] = (f32x2){z1.z, z1.w};
                zz[4] = (f32x2){z2.x, z2.y}; zz[5] = (f32x2){z2.z, z2.w};
                zz[6] = (f32x2){z3.x, z3.y}; zz[7] = (f32x2){z3.z, z3.w};
                zz[8] = (f32x2){z4.x, z4.y}; zz[9] = (f32x2){z4.z, z4.w};
            }
            f32x2 zd0 = (f32x2){0.0f, 0.0f}, zd1 = (f32x2){0.0f, 0.0f};
            f32x2 zs2 = (f32x2){0.0f, 0.0f};
#pragma unroll
            for (int j = 0; j < 10; ++j) {
                zd0 = pkfma(zz[j], wez0[j], zd0);
                zd1 = pkfma(zz[j], wez1[j], zd1);
                zs2 = zs2 + zz[j];
            }
            const float zsum = zs2.x + zs2.y;
            const float pinv = (t == 0) ? 0.0f : rcp_fast(zsum);
            f32x2 ev0 = (f32x2){fmaf(zd0.x + zd0.y, pinv, be0), 0.0f};
            f32x2 ev1 = (f32x2){fmaf(zd1.x + zd1.y, pinv, be1), 0.0f};
#pragma unroll
            for (int k = 0; k < 5; ++k) {
                ev0 = pkfma(y2[k], wey0[k], ev0);
                ev1 = pkfma(y2[k], wey1[k], ev1);
            }
            const float zv0 = exp2_fast(fminf((ev0.x + ev0.y) * LOG2E, 86.0f));
            const float zv1 = exp2_fast(fminf((ev1.x + ev1.y) * LOG2E, 86.0f));
            gZ[q] = zv0;
            if (he1) gZ[16 + q] = zv1;
            // no trailing fence: next step's fences precede the gZ read; chunk
            // boundaries are covered by __syncthreads.
        }

        __syncthreads();
        do_head(c);
        if (c + 1 < NCHUNK) do_xproj(c + 1);
        __syncthreads();
    }

    // ---- epilogue: reduce head partials across the CH t-row lanes, add static ----
    float* wred = reinterpret_cast<float*>(xb);   // xb dead; reuse as [16][CH][8]
    if (q < CH) {
        float* d = wred + (size_t)(g * CH + q) * 8;
        *reinterpret_cast<f32x2*>(d + 0) = p2[0];
        *reinterpret_cast<f32x2*>(d + 2) = p2[1];
        *reinterpret_cast<f32x2*>(d + 4) = p2[2];
        *reinterpret_cast<f32x2*>(d + 6) = p2[3];
    }
    __syncthreads();
    if (q < OUT_DIM) {
        float o = 0.0f;
        for (int r = 0; r < CH; ++r) o += wred[(size_t)(g * CH + r) * 8 + q];
        const float* stp = static_data + (size_t)traj * S_STAT;
        const float* wms = W_mlp + (size_t)(T_STEPS * L_DIM) * OUT_DIM;
#pragma unroll
        for (int i = 0; i < S_STAT; ++i) o += stp[i] * wms[i * OUT_DIM + q];
        out[(size_t)traj * OUT_DIM + q] = o + b_mlp[q];
    }
}

extern "C" void kernel_launch(void* const* d_in, const int* in_sizes, int n_in,
                              void* d_out, int out_size, void* d_ws, size_t ws_size,
                              hipStream_t stream) {
    const float* data        = (const float*)d_in[0];
    const float* time_steps  = (const float*)d_in[1];
    const float* static_data = (const float*)d_in[2];
    const float* W_update    = (const float*)d_in[3];
    const float* b_update    = (const float*)d_in[4];
    const float* W_reset     = (const float*)d_in[5];
    const float* b_reset     = (const float*)d_in[6];
    const float* W_new       = (const float*)d_in[7];
    const float* b_new       = (const float*)d_in[8];
    const float* W_emit      = (const float*)d_in[9];
    const float* b_emit      = (const float*)d_in[10];
    const float* W_ode       = (const float*)d_in[11];
    const float* b_ode       = (const float*)d_in[12];
    const float* W_mlp       = (const float*)d_in[13];
    const float* b_mlp       = (const float*)d_in[14];
    float* out = (float*)d_out;

    // 16 trajectories per 256-thread block -> 1024 blocks, 4096 waves
    dim3 grid(B_TRAJ / NG), block(256);
    hipLaunchKernelGGL(dgm2_v10, grid, block, 0, stream,
                       data, time_steps, static_data,
                       W_update, b_update, W_reset, b_reset, W_new, b_new,
                       W_emit, b_emit, W_ode, b_ode, W_mlp, b_mlp, out);
}

// Round 7
// 436.105 us; speedup vs baseline: 1.6934x; 1.6934x over previous
//
#include <hip/hip_runtime.h>
#include <hip/hip_fp16.h>
#include <math.h>

// Problem constants (from reference)
#define B_TRAJ 16384
#define T_STEPS 60
#define D_IN 36
#define L_DIM 10
#define C_NUM 20
#define S_STAT 9
#define OUT_DIM 8
#define XPW 1800              // half2 per traj-PAIR xproj: 60 t * 30 cols (u0-9,r0-9,n0-9)
#define SCW 152               // scratch floats per group: A@0 (72), B@72 (72), pad 8
                              // 152%32==24 -> group bases stagger banks 0/24/16/8

#define LOG2E 1.4426950408889634f

typedef float f32x2 __attribute__((ext_vector_type(2)));
__device__ __forceinline__ f32x2 pkfma(f32x2 a, f32x2 b, f32x2 c) {
    // llvm.fma.v2f32 -> v_pk_fma_f32 on gfx950 (full-rate packed f32)
    return __builtin_elementwise_fma(a, b, c);
}
__device__ __forceinline__ float rcp_fast(float x) { return __builtin_amdgcn_rcpf(x); }
__device__ __forceinline__ float exp2_fast(float x) { return __builtin_amdgcn_exp2f(x); }
__device__ __forceinline__ float sigm_fast(float x) {
    return rcp_fast(1.0f + exp2_fast(x * -LOG2E));
}
__device__ __forceinline__ float tanh_fast(float x) {
    const float t = fminf(fmaxf(x * (2.0f * LOG2E), -30.0f), 30.0f);
    return fmaf(-2.0f, rcp_fast(exp2_fast(t) + 1.0f), 1.0f);
}
#define WFENCE() __builtin_amdgcn_wave_barrier()

// v11: two trajectories PER LANE (ILP x2). v9's 16-lane-group scan math,
// duplicated into two independent chains (A,B) sharing weights and fences —
// chain A's VALU hides chain B's LDS latency and vice versa. xproj stored as
// __half2(A,B): one b32 read per gate serves both trajs; y-stash likewise.
// 64-thread wave = 4 groups x 2 trajs = 8 trajs/wave. LDS 31.5 KB -> 5
// blocks/CU. NO waves_per_eu cap (v10's spill lesson). All sync intra-wave.
__global__ __launch_bounds__(64)
void dgm2_v11(
    const float* __restrict__ data,        // [B, T, D]
    const float* __restrict__ time_steps,  // [T]
    const float* __restrict__ static_data, // [B, S]
    const float* __restrict__ W_update,    // [46, 10]
    const float* __restrict__ b_update,
    const float* __restrict__ W_reset,     // [46, 10]
    const float* __restrict__ b_reset,
    const float* __restrict__ W_new,       // [46, 10]
    const float* __restrict__ b_new,
    const float* __restrict__ W_emit,      // [30, 20]
    const float* __restrict__ b_emit,
    const float* __restrict__ W_ode,       // [10, 10]
    const float* __restrict__ b_ode,
    const float* __restrict__ W_mlp,       // [609, 8]
    const float* __restrict__ b_mlp,
    float* __restrict__ out)               // [B, 8]
{
    __shared__ __align__(16) __half2 xb2[4 * XPW];   // 28800 B: [pair][t*30 + col] (A,B)
    __shared__ __align__(16) float   sc[4 * SCW];    //  2432 B: per-group scratch
                                                      //   per traj: YI@0(16) YR@16(16) Y@32(16) Z@48(20)
    __shared__ float dts[T_STEPS];                   //   240 B  => 31472 B -> 5 blocks/CU

    const int tid   = threadIdx.x;
    const int grp   = tid >> 4;     // group: 2 trajs
    const int q     = tid & 15;     // lane within group
    const int trajA = blockIdx.x * 8 + grp * 2;   // trajB = trajA + 1
    __half2* xpj = xb2 + grp * XPW;

    if (tid < T_STEPS) dts[tid] = (tid == 0) ? 0.01f : time_steps[tid] - time_steps[tid - 1];
    WFENCE();   // single wave: DS in-order; compiler fence only

    const bool qg = (q < 10);
    const int  qc = qg ? q : 0;     // clamped gate col for lanes 10-15 (garbage-safe)

    // ================= Phase 1: xproj precompute (both trajs) =================
    // lane q handles cols c0=q (0..15), c1=16+q (q<14); col space 0-9 u, 10-19 r, 20-29 n.
    {
        const int  c0   = q;
        const bool has1 = (q < 14);
        const int  c1   = has1 ? 16 + q : 29;
        const float* W0 = (c0 < 10) ? W_update : W_reset;   // c0 <= 15: never W_new
        const int   cc0 = (c0 < 10) ? c0 : c0 - 10;
        const float* W1 = (c1 < 20) ? W_reset : W_new;      // c1 >= 16: never W_update
        const int   cc1 = (c1 < 20) ? c1 - 10 : c1 - 20;

        f32x2 wxp0[18], wxp1[18];   // x-part rows 10..45, k-packed
#pragma unroll
        for (int j = 0; j < 18; ++j) {
            wxp0[j] = (f32x2){W0[(L_DIM + 2 * j) * L_DIM + cc0],
                              W0[(L_DIM + 2 * j + 1) * L_DIM + cc0]};
            const f32x2 v1 = (f32x2){W1[(L_DIM + 2 * j) * L_DIM + cc1],
                                     W1[(L_DIM + 2 * j + 1) * L_DIM + cc1]};
            wxp1[j] = has1 ? v1 : (f32x2){0.0f, 0.0f};
        }
        const float b0 = (c0 < 10) ? b_update[c0] : b_reset[c0 - 10];
        const float b1 = has1 ? ((c1 < 20) ? b_reset[c1 - 10] : b_new[c1 - 20]) : 0.0f;

        const float* xA = data + (size_t)trajA * (T_STEPS * D_IN);
        const float* xB = xA + T_STEPS * D_IN;
        for (int t = 0; t < T_STEPS; ++t) {
            const float* rA = xA + t * D_IN;
            const float* rB = xB + t * D_IN;
            f32x2 a0A = (f32x2){b0, 0.0f}, a0B = (f32x2){b0, 0.0f};
            f32x2 a1A = (f32x2){b1, 0.0f}, a1B = (f32x2){b1, 0.0f};
#pragma unroll
            for (int c = 0; c < 9; ++c) {
                const float4 vA = *reinterpret_cast<const float4*>(rA + c * 4);
                const float4 vB = *reinterpret_cast<const float4*>(rB + c * 4);
                const f32x2 aLo = (f32x2){vA.x, vA.y}, aHi = (f32x2){vA.z, vA.w};
                const f32x2 bLo = (f32x2){vB.x, vB.y}, bHi = (f32x2){vB.z, vB.w};
                a0A = pkfma(aLo, wxp0[2 * c], a0A); a0A = pkfma(aHi, wxp0[2 * c + 1], a0A);
                a0B = pkfma(bLo, wxp0[2 * c], a0B); a0B = pkfma(bHi, wxp0[2 * c + 1], a0B);
                a1A = pkfma(aLo, wxp1[2 * c], a1A); a1A = pkfma(aHi, wxp1[2 * c + 1], a1A);
                a1B = pkfma(bLo, wxp1[2 * c], a1B); a1B = pkfma(bHi, wxp1[2 * c + 1], a1B);
            }
            xpj[t * 30 + c0] = __halves2half2(__float2half(a0A.x + a0A.y),
                                              __float2half(a0B.x + a0B.y));
            if (has1)
                xpj[t * 30 + c1] = __halves2half2(__float2half(a1A.x + a1A.y),
                                                  __float2half(a1B.x + a1B.y));
        }
    }
    WFENCE();

    // ================= Phase 2: sequential scan (chains A and B) =================
    f32x2 wode2[5], wu2[5], wr2[5], wn2[5];   // y-part cols (rows 0..9), k-packed
#pragma unroll
    for (int j = 0; j < 5; ++j) {
        if (qg) {
            wode2[j] = (f32x2){W_ode[(2 * j) * L_DIM + q], W_ode[(2 * j + 1) * L_DIM + q]};
            wu2[j]   = (f32x2){W_update[(2 * j) * L_DIM + q], W_update[(2 * j + 1) * L_DIM + q]};
            wr2[j]   = (f32x2){W_reset[(2 * j) * L_DIM + q], W_reset[(2 * j + 1) * L_DIM + q]};
            wn2[j]   = (f32x2){W_new[(2 * j) * L_DIM + q], W_new[(2 * j + 1) * L_DIM + q]};
        } else {
            wode2[j] = wu2[j] = wr2[j] = wn2[j] = (f32x2){0.0f, 0.0f};
        }
    }
    const float bode = qg ? b_ode[q] : 0.0f;

    const int  e0  = q;
    const bool he1 = (q < 4);
    const int  e1  = he1 ? 16 + q : 19;
    f32x2 wez0[10], wez1[10], wey0[5], wey1[5];
#pragma unroll
    for (int j = 0; j < 10; ++j) {
        wez0[j] = (f32x2){W_emit[(2 * j) * C_NUM + e0], W_emit[(2 * j + 1) * C_NUM + e0]};
        const f32x2 v1 = (f32x2){W_emit[(2 * j) * C_NUM + e1], W_emit[(2 * j + 1) * C_NUM + e1]};
        wez1[j] = he1 ? v1 : (f32x2){0.0f, 0.0f};
    }
#pragma unroll
    for (int j = 0; j < 5; ++j) {
        wey0[j] = (f32x2){W_emit[(C_NUM + 2 * j) * C_NUM + e0],
                          W_emit[(C_NUM + 2 * j + 1) * C_NUM + e0]};
        const f32x2 v1 = (f32x2){W_emit[(C_NUM + 2 * j) * C_NUM + e1],
                                 W_emit[(C_NUM + 2 * j + 1) * C_NUM + e1]};
        wey1[j] = he1 ? v1 : (f32x2){0.0f, 0.0f};
    }
    const float be0 = b_emit[e0];
    const float be1 = he1 ? b_emit[e1] : 0.0f;

    float* gA = sc + grp * SCW;    // traj A scratch: YI@0 YR@16 Y@32 Z@48
    float* gB = gA + 72;           // traj B scratch (same layout)

    auto ldvec = [&](const float* p, f32x2* d) {
        const float4 a = *reinterpret_cast<const float4*>(p);
        const float4 b = *reinterpret_cast<const float4*>(p + 4);
        const float2 c = *reinterpret_cast<const float2*>(p + 8);
        d[0] = (f32x2){a.x, a.y}; d[1] = (f32x2){a.z, a.w};
        d[2] = (f32x2){b.x, b.y}; d[3] = (f32x2){b.z, b.w};
        d[4] = (f32x2){c.x, c.y};
    };
    auto ldz = [&](const float* p, f32x2* d) {
#pragma unroll
        for (int j = 0; j < 5; ++j) {
            const float4 z = *reinterpret_cast<const float4*>(p + j * 4);
            d[2 * j] = (f32x2){z.x, z.y}; d[2 * j + 1] = (f32x2){z.z, z.w};
        }
    };

    f32x2 y2A[5], y2B[5];
#pragma unroll
    for (int k = 0; k < 5; ++k) { y2A[k] = (f32x2){0.0f, 0.0f}; y2B[k] = (f32x2){0.0f, 0.0f}; }
    float yownA = 0.0f, yownB = 0.0f;
    gA[48 + q] = 0.0f; gB[48 + q] = 0.0f;          // carried unnormalized z
    if (he1) { gA[64 + q] = 0.0f; gB[64 + q] = 0.0f; }
    WFENCE();

    for (int t = 0; t < T_STEPS; ++t) {
        const float dt = dts[t];

        // ---- ODE (both chains): yi_q = y_q + tanh(b + y.Wode[:,q])*dt ----
        f32x2 gdA = (f32x2){bode, 0.0f}, gdB = (f32x2){bode, 0.0f};
#pragma unroll
        for (int k = 0; k < 5; ++k) {
            gdA = pkfma(y2A[k], wode2[k], gdA);
            gdB = pkfma(y2B[k], wode2[k], gdB);
        }
        const float yisA = fmaf(tanh_fast(gdA.x + gdA.y), dt, yownA);
        const float yisB = fmaf(tanh_fast(gdB.x + gdB.y), dt, yownB);
        gA[q] = yisA; gB[q] = yisB;
        WFENCE();
        f32x2 yiA[5], yiB[5];
        ldvec(gA, yiA); ldvec(gB, yiB);

        // xproj: one b32 per gate serves both trajs (bias folded)
        const float2 xu = __half22float2(xpj[t * 30 + qc]);
        const float2 xr = __half22float2(xpj[t * 30 + 10 + qc]);
        const float2 xn = __half22float2(xpj[t * 30 + 20 + qc]);

        // ---- gates (both chains) ----
        f32x2 auA = (f32x2){xu.x, 0.0f}, arA = (f32x2){xr.x, 0.0f};
        f32x2 auB = (f32x2){xu.y, 0.0f}, arB = (f32x2){xr.y, 0.0f};
#pragma unroll
        for (int k = 0; k < 5; ++k) {
            auA = pkfma(yiA[k], wu2[k], auA); arA = pkfma(yiA[k], wr2[k], arA);
            auB = pkfma(yiB[k], wu2[k], auB); arB = pkfma(yiB[k], wr2[k], arB);
        }
        const float uA = sigm_fast(auA.x + auA.y), rA = sigm_fast(arA.x + arA.y);
        const float uB = sigm_fast(auB.x + auB.y), rB = sigm_fast(arB.x + arB.y);
        gA[16 + q] = rA * yisA; gB[16 + q] = rB * yisB;
        WFENCE();
        f32x2 yrA[5], yrB[5];
        ldvec(gA + 16, yrA); ldvec(gB + 16, yrB);

        // ---- candidate + blend (lane-local, both chains) ----
        f32x2 anA = (f32x2){xn.x, 0.0f}, anB = (f32x2){xn.y, 0.0f};
#pragma unroll
        for (int k = 0; k < 5; ++k) {
            anA = pkfma(yrA[k], wn2[k], anA);
            anB = pkfma(yrB[k], wn2[k], anB);
        }
        const float nvA = anA.x + anA.y, nvB = anB.x + anB.y;
        const float ynA = fmaf(uA, yisA - nvA, nvA);
        const float ynB = fmaf(uB, yisB - nvB, nvB);
        yownA = ynA; yownB = ynB;
        gA[32 + q] = ynA; gB[32 + q] = ynB;
        if (qg) xpj[t * 30 + q] = __halves2half2(__float2half(ynA), __float2half(ynB)); // y stash
        WFENCE();
        ldvec(gA + 32, y2A); ldvec(gB + 32, y2B);

        // ---- emitter (both chains): logit_c = b + (z.We_p[:,c])/sum(z) + y.We_y[:,c] ----
        f32x2 zzA[10], zzB[10];
        ldz(gA + 48, zzA); ldz(gB + 48, zzB);
        f32x2 zd0A = {}, zd1A = {}, zsA2 = {}, zd0B = {}, zd1B = {}, zsB2 = {};
#pragma unroll
        for (int j = 0; j < 10; ++j) {
            zd0A = pkfma(zzA[j], wez0[j], zd0A); zd1A = pkfma(zzA[j], wez1[j], zd1A);
            zsA2 = zsA2 + zzA[j];
            zd0B = pkfma(zzB[j], wez0[j], zd0B); zd1B = pkfma(zzB[j], wez1[j], zd1B);
            zsB2 = zsB2 + zzB[j];
        }
        const float pinvA = (t == 0) ? 0.0f : rcp_fast(zsA2.x + zsA2.y);
        const float pinvB = (t == 0) ? 0.0f : rcp_fast(zsB2.x + zsB2.y);
        f32x2 e0A = (f32x2){fmaf(zd0A.x + zd0A.y, pinvA, be0), 0.0f};
        f32x2 e1A = (f32x2){fmaf(zd1A.x + zd1A.y, pinvA, be1), 0.0f};
        f32x2 e0B = (f32x2){fmaf(zd0B.x + zd0B.y, pinvB, be0), 0.0f};
        f32x2 e1B = (f32x2){fmaf(zd1B.x + zd1B.y, pinvB, be1), 0.0f};
#pragma unroll
        for (int k = 0; k < 5; ++k) {
            e0A = pkfma(y2A[k], wey0[k], e0A); e1A = pkfma(y2A[k], wey1[k], e1A);
            e0B = pkfma(y2B[k], wey0[k], e0B); e1B = pkfma(y2B[k], wey1[k], e1B);
        }
        gA[48 + q] = exp2_fast(fminf((e0A.x + e0A.y) * LOG2E, 86.0f));
        gB[48 + q] = exp2_fast(fminf((e0B.x + e0B.y) * LOG2E, 86.0f));
        if (he1) {
            gA[64 + q] = exp2_fast(fminf((e1A.x + e1A.y) * LOG2E, 86.0f));
            gB[64 + q] = exp2_fast(fminf((e1B.x + e1B.y) * LOG2E, 86.0f));
        }
        // no trailing fence: next step's fences precede the z read.
    }

    // ================= Phase 3: deferred MLP head =================
    // 16 lanes per group: tr = q>>3 picks traj, col = q&7.
    WFENCE();
    {
        const int col = q & 7, tr = q >> 3;
        float o = 0.0f;
        for (int t = 0; t < T_STEPS; ++t) {
            const __half2* yh = xpj + t * 30;     // y stash cols 0..9 (A,B)
            const float* wr = W_mlp + (size_t)t * (L_DIM * OUT_DIM) + col;
#pragma unroll
            for (int j = 0; j < 5; ++j) {
                union { float2 f; __half2 h[2]; } u2;
                u2.f = *reinterpret_cast<const float2*>(yh + 2 * j);
                const float2 p0 = __half22float2(u2.h[0]);
                const float2 p1 = __half22float2(u2.h[1]);
                const float v0 = tr ? p0.y : p0.x;
                const float v1 = tr ? p1.y : p1.x;
                o = fmaf(v0, wr[(2 * j) * OUT_DIM], o);
                o = fmaf(v1, wr[(2 * j + 1) * OUT_DIM], o);
            }
        }
        const int traj = trajA + tr;
        const float* stp = static_data + (size_t)traj * S_STAT;
        const float* wms = W_mlp + (size_t)(T_STEPS * L_DIM) * OUT_DIM;
#pragma unroll
        for (int i = 0; i < S_STAT; ++i) o += stp[i] * wms[i * OUT_DIM + col];
        out[(size_t)traj * OUT_DIM + col] = o + b_mlp[col];
    }
}

extern "C" void kernel_launch(void* const* d_in, const int* in_sizes, int n_in,
                              void* d_out, int out_size, void* d_ws, size_t ws_size,
                              hipStream_t stream) {
    const float* data        = (const float*)d_in[0];
    const float* time_steps  = (const float*)d_in[1];
    const float* static_data = (const float*)d_in[2];
    const float* W_update    = (const float*)d_in[3];
    const float* b_update    = (const float*)d_in[4];
    const float* W_reset     = (const float*)d_in[5];
    const float* b_reset     = (const float*)d_in[6];
    const float* W_new       = (const float*)d_in[7];
    const float* b_new       = (const float*)d_in[8];
    const float* W_emit      = (const float*)d_in[9];
    const float* b_emit      = (const float*)d_in[10];
    const float* W_ode       = (const float*)d_in[11];
    const float* b_ode       = (const float*)d_in[12];
    const float* W_mlp       = (const float*)d_in[13];
    const float* b_mlp       = (const float*)d_in[14];
    float* out = (float*)d_out;

    // 8 trajectories per 64-thread block (one wave) -> 2048 blocks
    dim3 grid(B_TRAJ / 8), block(64);
    hipLaunchKernelGGL(dgm2_v11, grid, block, 0, stream,
                       data, time_steps, static_data,
                       W_update, b_update, W_reset, b_reset, W_new, b_new,
                       W_emit, b_emit, W_ode, b_ode, W_mlp, b_mlp, out);
}